// Round 1
// baseline (1897.637 us; speedup 1.0000x reference)
//
#include <hip/hip_runtime.h>
#include <hip/hip_bf16.h>

// Problem constants (fixed by the reference)
#define NN 8192
#define EE 131072
#define MUL 128
#define AA 10
#define RB 8
#define DEF 264          // RB + 2*MUL
#define INV_SQRT3 0.5773502691896258f
#define INV_SQRT128 0.08838834764831845f
#define INV_SQRT10 0.31622776601683794f
#define INV_SQRT264 0.06154574548966636f

// Workspace layout (float offsets)
#define WS_US    ((size_t)0)                    // N*128
#define WS_UV    ((size_t)NN*128)               // N*384
#define WS_SRC   (WS_UV + (size_t)NN*384)       // N*128
#define WS_TGT   (WS_SRC + (size_t)NN*128)      // N*128
#define WS_MSGS  (WS_TGT + (size_t)NN*128)      // N*256
#define WS_MSGV  (WS_MSGS + (size_t)NN*256)     // N*768
#define WS_DENS  (WS_MSGV + (size_t)NN*768)     // N
#define WS_END   (WS_DENS + (size_t)NN)

__device__ __forceinline__ float silu_f(float x) { return x / (1.f + __expf(-x)); }
__device__ __forceinline__ float sigm_f(float x) { return 1.f / (1.f + __expf(-x)); }

// ---------------------------------------------------------------------------
// Kernel A: per-node precompute.
//   sc (to d_out), us, uv, src_e, tgt_e (to ws)
// block = 128 threads, 8 nodes/block
// ---------------------------------------------------------------------------
#define NPB_A 8
__global__ __launch_bounds__(128) void node_pre(
    const float* __restrict__ node_attrs, const float* __restrict__ node_feats,
    const float* __restrict__ Wss, const float* __restrict__ Wsv,
    const float* __restrict__ Wus, const float* __restrict__ Wuv,
    const float* __restrict__ Wsrc, const float* __restrict__ Wtgt,
    float* __restrict__ sc_out, float* __restrict__ us, float* __restrict__ uv,
    float* __restrict__ srcE, float* __restrict__ tgtE)
{
    __shared__ float s_l[NPB_A][128];
    __shared__ float v_l[NPB_A][384];
    __shared__ float a_l[NPB_A][AA];
    const int j = threadIdx.x;
    const int n0 = blockIdx.x * NPB_A;

    for (int idx = j; idx < NPB_A * 512; idx += 128) {
        int e = idx >> 9, k = idx & 511;
        float val = node_feats[(size_t)(n0 + e) * 512 + k];
        if (k < 128) s_l[e][k] = val; else v_l[e][k - 128] = val;
    }
    for (int idx = j; idx < NPB_A * AA; idx += 128) {
        int e = idx / AA, k = idx - e * AA;
        a_l[e][k] = node_attrs[(size_t)(n0 + e) * AA + k];
    }
    __syncthreads();

    float accS[NPB_A] = {0}, accU[NPB_A] = {0};
    float accSV[NPB_A][3] = {{0}}, accUV[NPB_A][3] = {{0}};
    float accSrc[NPB_A] = {0}, accTgt[NPB_A] = {0};

#pragma unroll 4
    for (int i = 0; i < 128; ++i) {
        float ws = Wss[i * 128 + j], wu = Wus[i * 128 + j];
#pragma unroll
        for (int e = 0; e < NPB_A; ++e) {
            float sv = s_l[e][i];
            accS[e] += sv * ws; accU[e] += sv * wu;
        }
    }
#pragma unroll 2
    for (int i = 0; i < 128; ++i) {
        float wsv = Wsv[i * 128 + j], wuv = Wuv[i * 128 + j];
#pragma unroll
        for (int e = 0; e < NPB_A; ++e) {
#pragma unroll
            for (int c = 0; c < 3; ++c) {
                float vv = v_l[e][i * 3 + c];
                accSV[e][c] += vv * wsv; accUV[e][c] += vv * wuv;
            }
        }
    }
#pragma unroll
    for (int i = 0; i < AA; ++i) {
        float w1 = Wsrc[i * 128 + j], w2 = Wtgt[i * 128 + j];
#pragma unroll
        for (int e = 0; e < NPB_A; ++e) {
            float av = a_l[e][i];
            accSrc[e] += av * w1; accTgt[e] += av * w2;
        }
    }

#pragma unroll
    for (int e = 0; e < NPB_A; ++e) {
        size_t n = n0 + e;
        sc_out[n * 512 + j] = accS[e] * INV_SQRT128;
#pragma unroll
        for (int c = 0; c < 3; ++c)
            sc_out[n * 512 + 128 + j * 3 + c] = accSV[e][c] * INV_SQRT128;
        us[n * 128 + j] = accU[e] * INV_SQRT128;
#pragma unroll
        for (int c = 0; c < 3; ++c)
            uv[n * 384 + j * 3 + c] = accUV[e][c] * INV_SQRT128;
        srcE[n * 128 + j] = accSrc[e] * INV_SQRT10;
        tgtE[n * 128 + j] = accTgt[e] * INV_SQRT10;
    }
}

// ---------------------------------------------------------------------------
// Kernel B: per-edge MLPs + tensor-product message + atomic scatter.
// block = 256 threads (4 waves), 16 edges/block, 4 edges/wave.
// ---------------------------------------------------------------------------
#define EB 16
__global__ __launch_bounds__(256) void edge_kernel(
    const float* __restrict__ edge_attrs, const float* __restrict__ edge_feats,
    const int* __restrict__ edge_index,
    const float* __restrict__ srcE, const float* __restrict__ tgtE,
    const float* __restrict__ us, const float* __restrict__ uv,
    const float* __restrict__ Wr0, const float* __restrict__ Wr1,
    const float* __restrict__ Wr2, const float* __restrict__ Wr3,
    const float* __restrict__ Wd0, const float* __restrict__ Wd1,
    float* __restrict__ msg_s, float* __restrict__ msg_v, float* __restrict__ density)
{
    __shared__ float ef[EB][DEF];
    __shared__ float xs[EB][128];
    __shared__ float xv[EB][384];
    __shared__ float hA[EB][64];
    __shared__ float hB[EB][64];
    __shared__ int   snd_l[EB], rcv_l[EB];
    __shared__ float y0_l[EB], y1_l[EB][3];

    const int t = threadIdx.x;
    const int j = t & 63;
    const int w = t >> 6;
    const int e0 = blockIdx.x * EB;

    if (t < EB) {
        snd_l[t] = edge_index[e0 + t];
        rcv_l[t] = edge_index[EE + e0 + t];
    }
    if (t >= 64 && t < 64 + EB * 4) {
        int tt = t - 64, e = tt >> 2, k = tt & 3;
        float v = edge_attrs[(size_t)(e0 + e) * 4 + k];
        if (k == 0) y0_l[e] = v; else y1_l[e][k - 1] = v;
    }
    __syncthreads();

    for (int idx = t; idx < EB * DEF; idx += 256) {
        int e = idx / DEF, k = idx - e * DEF;
        float v;
        if (k < RB)            v = edge_feats[(size_t)(e0 + e) * RB + k];
        else if (k < RB + 128) v = srcE[(size_t)snd_l[e] * 128 + (k - RB)];
        else                   v = tgtE[(size_t)rcv_l[e] * 128 + (k - RB - 128)];
        ef[e][k] = v;
    }
    for (int idx = t; idx < EB * 128; idx += 256) {
        int e = idx >> 7, k = idx & 127;
        xs[e][k] = us[(size_t)snd_l[e] * 128 + k];
    }
    for (int idx = t; idx < EB * 384; idx += 256) {
        int e = idx / 384, k = idx - e * 384;
        xv[e][k] = uv[(size_t)snd_l[e] * 384 + k];
    }
    __syncthreads();

    const int eb = w * 4;

    // h0 = silu(ef @ Wr0 / sqrt(264)); d = silu(ef @ Wd0 / sqrt(264))
    float acc[4] = {0, 0, 0, 0}, dac[4] = {0, 0, 0, 0};
#pragma unroll 2
    for (int i = 0; i < DEF; ++i) {
        float wr = Wr0[i * 64 + j], wd = Wd0[i * 64 + j];
#pragma unroll
        for (int k2 = 0; k2 < 4; ++k2) {
            float v = ef[eb + k2][i];
            acc[k2] += v * wr; dac[k2] += v * wd;
        }
    }
    float dreg[4];
#pragma unroll
    for (int k2 = 0; k2 < 4; ++k2) {
        hA[eb + k2][j] = silu_f(acc[k2] * INV_SQRT264);
        dreg[k2] = silu_f(dac[k2] * INV_SQRT264);
    }
    // edge density: tanh((d . Wd1 / 8)^2) -> atomic add
    {
        float wd1 = Wd1[j];
        float p[4];
#pragma unroll
        for (int k2 = 0; k2 < 4; ++k2) p[k2] = dreg[k2] * wd1;
#pragma unroll
        for (int m = 1; m < 64; m <<= 1) {
#pragma unroll
            for (int k2 = 0; k2 < 4; ++k2) p[k2] += __shfl_xor(p[k2], m);
        }
        if (j == 0) {
#pragma unroll
            for (int k2 = 0; k2 < 4; ++k2) {
                float tq = p[k2] * 0.125f;
                atomicAdd(&density[rcv_l[eb + k2]], tanhf(tq * tq));
            }
        }
    }
    __syncthreads();

    // h1 = silu(h0 @ Wr1 / 8)
#pragma unroll
    for (int k2 = 0; k2 < 4; ++k2) acc[k2] = 0.f;
#pragma unroll 4
    for (int i = 0; i < 64; ++i) {
        float wr = Wr1[i * 64 + j];
#pragma unroll
        for (int k2 = 0; k2 < 4; ++k2) acc[k2] += hA[eb + k2][i] * wr;
    }
    __syncthreads();
#pragma unroll
    for (int k2 = 0; k2 < 4; ++k2) hB[eb + k2][j] = silu_f(acc[k2] * 0.125f);
    __syncthreads();

    // h2 = silu(h1 @ Wr2 / 8)
#pragma unroll
    for (int k2 = 0; k2 < 4; ++k2) acc[k2] = 0.f;
#pragma unroll 4
    for (int i = 0; i < 64; ++i) {
        float wr = Wr2[i * 64 + j];
#pragma unroll
        for (int k2 = 0; k2 < 4; ++k2) acc[k2] += hB[eb + k2][i] * wr;
    }
    __syncthreads();
#pragma unroll
    for (int k2 = 0; k2 < 4; ++k2) hA[eb + k2][j] = silu_f(acc[k2] * 0.125f);
    __syncthreads();

    // tpw = h2 @ Wr3 / 8, in 8 chunks of 64 outputs; fuse message + scatter
    for (int q = 0; q < 8; ++q) {
        float a2[4] = {0, 0, 0, 0};
#pragma unroll 4
        for (int i = 0; i < 64; ++i) {
            float wr = Wr3[i * 512 + q * 64 + j];
#pragma unroll
            for (int k2 = 0; k2 < 4; ++k2) a2[k2] += hA[eb + k2][i] * wr;
        }
        const int u = (q & 1) * 64 + j;
        if (q < 2) {            // w1 * xs * y0 -> msg_s[:, u]
#pragma unroll
            for (int k2 = 0; k2 < 4; ++k2) {
                int e = eb + k2;
                float val = a2[k2] * 0.125f * xs[e][u] * y0_l[e];
                atomicAdd(&msg_s[(size_t)rcv_l[e] * 256 + u], val);
            }
        } else if (q < 4) {     // (w2*xs) y1[c] /sqrt3 -> msg_v[:, u, c]
#pragma unroll
            for (int k2 = 0; k2 < 4; ++k2) {
                int e = eb + k2;
                float base = a2[k2] * 0.125f * xs[e][u] * INV_SQRT3;
                size_t o = (size_t)rcv_l[e] * 768 + u * 3;
#pragma unroll
                for (int c = 0; c < 3; ++c)
                    atomicAdd(&msg_v[o + c], base * y1_l[e][c]);
            }
        } else if (q < 6) {     // w3 * xv * y0 /sqrt3 -> msg_v[:, 128+u, c]
#pragma unroll
            for (int k2 = 0; k2 < 4; ++k2) {
                int e = eb + k2;
                float base = a2[k2] * 0.125f * y0_l[e] * INV_SQRT3;
                size_t o = (size_t)rcv_l[e] * 768 + (128 + u) * 3;
#pragma unroll
                for (int c = 0; c < 3; ++c)
                    atomicAdd(&msg_v[o + c], base * xv[e][u * 3 + c]);
            }
        } else {                // w4 * (xv.y1) /sqrt3 -> msg_s[:, 128+u]
#pragma unroll
            for (int k2 = 0; k2 < 4; ++k2) {
                int e = eb + k2;
                float dotv = xv[e][u * 3] * y1_l[e][0] + xv[e][u * 3 + 1] * y1_l[e][1]
                           + xv[e][u * 3 + 2] * y1_l[e][2];
                atomicAdd(&msg_s[(size_t)rcv_l[e] * 256 + 128 + u],
                          a2[k2] * 0.125f * dotv * INV_SQRT3);
            }
        }
    }
}

// ---------------------------------------------------------------------------
// Kernel C: per-node epilogue (W1/Wres, gate, W2) -> out
// block = 128 threads, 8 nodes/block
// ---------------------------------------------------------------------------
#define NPB_C 8
__global__ __launch_bounds__(128) void node_post(
    const float* __restrict__ msg_s, const float* __restrict__ msg_v,
    const float* __restrict__ density,
    const float* __restrict__ us, const float* __restrict__ uv,
    const float* __restrict__ W1s, const float* __restrict__ W1v,
    const float* __restrict__ Wrs, const float* __restrict__ Wrv,
    const float* __restrict__ W2s, const float* __restrict__ W2v,
    const float* __restrict__ alpha_p, const float* __restrict__ beta_p,
    float* __restrict__ out)
{
    __shared__ float ms_l[NPB_C][256];
    __shared__ float mv_l[NPB_C][768];
    __shared__ float us_l[NPB_C][128];
    __shared__ float uv_l[NPB_C][384];
    __shared__ float den_l[NPB_C];
    const int j = threadIdx.x;
    const int n0 = blockIdx.x * NPB_C;
    const float alpha = *alpha_p, beta = *beta_p;

    for (int idx = j; idx < NPB_C * 256; idx += 128) {
        int e = idx >> 8, k = idx & 255;
        ms_l[e][k] = msg_s[(size_t)(n0 + e) * 256 + k];
    }
    for (int idx = j; idx < NPB_C * 768; idx += 128) {
        int e = idx / 768, k = idx - e * 768;
        mv_l[e][k] = msg_v[(size_t)(n0 + e) * 768 + k];
    }
    for (int idx = j; idx < NPB_C * 128; idx += 128) {
        int e = idx >> 7, k = idx & 127;
        us_l[e][k] = us[(size_t)(n0 + e) * 128 + k];
    }
    for (int idx = j; idx < NPB_C * 384; idx += 128) {
        int e = idx / 384, k = idx - e * 384;
        uv_l[e][k] = uv[(size_t)(n0 + e) * 384 + k];
    }
    if (j < NPB_C) den_l[j] = density[n0 + j];
    __syncthreads();

    float mA[NPB_C] = {0}, mB[NPB_C] = {0}, mV[NPB_C][3] = {{0}};
#pragma unroll 2
    for (int i = 0; i < 256; ++i) {
        float w1 = W1s[i * 256 + j], w2 = W1s[i * 256 + 128 + j], wv = W1v[i * 128 + j];
#pragma unroll
        for (int e = 0; e < NPB_C; ++e) {
            float msv = ms_l[e][i];
            mA[e] += msv * w1; mB[e] += msv * w2;
#pragma unroll
            for (int c = 0; c < 3; ++c) mV[e][c] += mv_l[e][i * 3 + c] * wv;
        }
    }
    float rA[NPB_C] = {0}, rB[NPB_C] = {0}, rV[NPB_C][3] = {{0}};
#pragma unroll 2
    for (int i = 0; i < 128; ++i) {
        float w1 = Wrs[i * 256 + j], w2 = Wrs[i * 256 + 128 + j], wv = Wrv[i * 128 + j];
#pragma unroll
        for (int e = 0; e < NPB_C; ++e) {
            float sv = us_l[e][i];
            rA[e] += sv * w1; rB[e] += sv * w2;
#pragma unroll
            for (int c = 0; c < 3; ++c) rV[e][c] += uv_l[e][i * 3 + c] * wv;
        }
    }
    __syncthreads();  // done reading us_l/uv_l; reuse as out_s/out_v

#pragma unroll
    for (int e = 0; e < NPB_C; ++e) {
        float invden = 1.f / (den_l[e] * beta + alpha);
        float m1 = mA[e] * 0.0625f * invden + rA[e] * INV_SQRT128;
        float m2 = mB[e] * 0.0625f * invden + rB[e] * INV_SQRT128;
        float gate = sigm_f(m2);
        us_l[e][j] = silu_f(m1);
#pragma unroll
        for (int c = 0; c < 3; ++c)
            uv_l[e][j * 3 + c] = (mV[e][c] * 0.0625f * invden + rV[e][c] * INV_SQRT128) * gate;
    }
    __syncthreads();

    float fS[NPB_C] = {0}, fV[NPB_C][3] = {{0}};
#pragma unroll 2
    for (int i = 0; i < 128; ++i) {
        float w1 = W2s[i * 128 + j], wv = W2v[i * 128 + j];
#pragma unroll
        for (int e = 0; e < NPB_C; ++e) {
            fS[e] += us_l[e][i] * w1;
#pragma unroll
            for (int c = 0; c < 3; ++c) fV[e][c] += uv_l[e][i * 3 + c] * wv;
        }
    }
#pragma unroll
    for (int e = 0; e < NPB_C; ++e) {
        size_t n = n0 + e;
        float4 o;
        o.x = fS[e] * INV_SQRT128;
        o.y = fV[e][0] * INV_SQRT128;
        o.z = fV[e][1] * INV_SQRT128;
        o.w = fV[e][2] * INV_SQRT128;
        reinterpret_cast<float4*>(out)[n * 128 + j] = o;
    }
}

// ---------------------------------------------------------------------------
extern "C" void kernel_launch(void* const* d_in, const int* in_sizes, int n_in,
                              void* d_out, int out_size, void* d_ws, size_t ws_size,
                              hipStream_t stream)
{
    const float* node_attrs = (const float*)d_in[0];
    const float* node_feats = (const float*)d_in[1];
    const float* edge_attrs = (const float*)d_in[2];
    const float* edge_feats = (const float*)d_in[3];
    const int*   edge_index = (const int*)d_in[4];
    const float* W_skip_s = (const float*)d_in[5];
    const float* W_skip_v = (const float*)d_in[6];
    const float* W_up_s   = (const float*)d_in[7];
    const float* W_up_v   = (const float*)d_in[8];
    const float* W_src    = (const float*)d_in[9];
    const float* W_tgt    = (const float*)d_in[10];
    const float* W_r0     = (const float*)d_in[11];
    const float* W_r1     = (const float*)d_in[12];
    const float* W_r2     = (const float*)d_in[13];
    const float* W_r3     = (const float*)d_in[14];
    const float* W_d0     = (const float*)d_in[15];
    const float* W_d1     = (const float*)d_in[16];
    const float* W1_s     = (const float*)d_in[17];
    const float* W1_v     = (const float*)d_in[18];
    const float* Wres_s   = (const float*)d_in[19];
    const float* Wres_v   = (const float*)d_in[20];
    const float* W2_s     = (const float*)d_in[21];
    const float* W2_v     = (const float*)d_in[22];
    const float* alpha_p  = (const float*)d_in[23];
    const float* beta_p   = (const float*)d_in[24];

    float* out = (float*)d_out;
    float* sc_out = out + (size_t)NN * 512;   // out part is N*128*4 = N*512 floats
    float* ws = (float*)d_ws;

    float* us   = ws + WS_US;
    float* uv   = ws + WS_UV;
    float* srcE = ws + WS_SRC;
    float* tgtE = ws + WS_TGT;
    float* msgS = ws + WS_MSGS;
    float* msgV = ws + WS_MSGV;
    float* dens = ws + WS_DENS;

    // zero the accumulators (msg_s, msg_v, density are contiguous)
    hipMemsetAsync(msgS, 0, (size_t)NN * (256 + 768 + 1) * sizeof(float), stream);

    node_pre<<<NN / NPB_A, 128, 0, stream>>>(
        node_attrs, node_feats, W_skip_s, W_skip_v, W_up_s, W_up_v, W_src, W_tgt,
        sc_out, us, uv, srcE, tgtE);

    edge_kernel<<<EE / EB, 256, 0, stream>>>(
        edge_attrs, edge_feats, edge_index, srcE, tgtE, us, uv,
        W_r0, W_r1, W_r2, W_r3, W_d0, W_d1, msgS, msgV, dens);

    node_post<<<NN / NPB_C, 128, 0, stream>>>(
        msgS, msgV, dens, us, uv, W1_s, W1_v, Wres_s, Wres_v, W2_s, W2_v,
        alpha_p, beta_p, out);
}